// Round 3
// baseline (409.248 us; speedup 1.0000x reference)
//
#include <hip/hip_runtime.h>
#include <stdint.h>

#define DEV static __device__ __forceinline__

typedef _Float16 half8 __attribute__((ext_vector_type(8)));
typedef _Float16 half4 __attribute__((ext_vector_type(4)));
typedef float f32x4 __attribute__((ext_vector_type(4)));

// Problem constants (B=2, S=2048, D=2048, H=16, HD=128)
constexpr int Bc = 2, Sc = 2048, Dc = 2048, Hc = 16, HDc = 128;
constexpr int D3c = 3 * Dc;   // 6144
constexpr int Mc = Bc * Sc;   // 4096

// -------- helpers --------
DEV void gl_lds16(const void* g, void* l) {
    // async 16B/lane global->LDS; LDS dest = wave-uniform base + lane*16
    __builtin_amdgcn_global_load_lds(
        (const __attribute__((address_space(1))) unsigned int*)g,
        (__attribute__((address_space(3))) unsigned int*)l,
        16, 0, 0);
}

// ============ fused preprocessing: cast x + transpose/cast Wqkv, Wo ============
DEV void transpose_tile(const float* __restrict__ in, _Float16* __restrict__ out,
                        int R, int C, int bx, int by, float (*ls)[65], int t)
{
    const int r0 = by * 64, c0 = bx * 64;
    const int rr = t >> 6, cc = t & 63;
#pragma unroll
    for (int i = 0; i < 16; ++i) {
        int r = i * 4 + rr;
        ls[r][cc] = in[(size_t)(r0 + r) * C + c0 + cc];
    }
    __syncthreads();
#pragma unroll
    for (int i = 0; i < 16; ++i) {
        int r = i * 4 + rr;
        out[(size_t)(c0 + r) * R + r0 + cc] = (_Float16)ls[cc][r];
    }
}

__global__ __launch_bounds__(256) void preproc_kernel(
    const float* __restrict__ x, const float* __restrict__ Wqkv,
    const float* __restrict__ Wo,
    _Float16* __restrict__ xb, _Float16* __restrict__ wt1, _Float16* __restrict__ wt2)
{
    __shared__ float ls[64][65];
    const int bid = blockIdx.x, t = threadIdx.x;
    if (bid < 4096) {
        // cast x -> f16, 8 elems/thread
        int i = bid * 256 + t;
        const float4* p = (const float4*)x;
        float4 a = p[i * 2], b = p[i * 2 + 1];
        half8 hv;
        hv[0] = (_Float16)a.x; hv[1] = (_Float16)a.y; hv[2] = (_Float16)a.z; hv[3] = (_Float16)a.w;
        hv[4] = (_Float16)b.x; hv[5] = (_Float16)b.y; hv[6] = (_Float16)b.z; hv[7] = (_Float16)b.w;
        *(half8*)(xb + (size_t)i * 8) = hv;
    } else if (bid < 4096 + 3072) {
        // Wqkv [2048][6144] -> wt1 [6144][2048]
        int tb = bid - 4096;
        transpose_tile(Wqkv, wt1, Dc, D3c, tb % 96, tb / 96, ls, t);
    } else {
        // Wo [2048][2048] -> wt2 [2048][2048]
        int tb = bid - 7168;
        transpose_tile(Wo, wt2, Dc, Dc, tb & 31, tb >> 5, ls, t);
    }
}

// ====== V transpose: qkv[b,s, h*384+256+d] -> vt[(bh*128+d)*2048 + s] ======
__global__ __launch_bounds__(256) void transpose_v_kernel(
    const uint16_t* __restrict__ qkv, uint16_t* __restrict__ vt)
{
    __shared__ uint32_t ls[64][65];
    const int t = threadIdx.x;
    const int s0 = blockIdx.x * 64, d0 = blockIdx.y * 64, bh = blockIdx.z;
    const int b = bh >> 4, h = bh & 15;
    const int rr = t >> 6, cc = t & 63;
#pragma unroll
    for (int i = 0; i < 16; ++i) {
        int r = i * 4 + rr;   // s index
        ls[r][cc] = qkv[(size_t)(b * Sc + s0 + r) * D3c + h * 384 + 256 + d0 + cc];
    }
    __syncthreads();
#pragma unroll
    for (int i = 0; i < 16; ++i) {
        int r = i * 4 + rr;   // d index
        vt[(size_t)(bh * HDc + d0 + r) * Sc + s0 + cc] = (uint16_t)ls[cc][r];
    }
}

// ======================= GEMM: C[M,N] = A[M,K] @ Bt[N,K]^T + bias =======================
// 128x128 tile, BK=64, 256 threads (2x2 waves of 64x64), f16 MFMA 16x16x32,
// global_load_lds staging with XOR-swizzled source pointers.
template <int BF16OUT>
__global__ __launch_bounds__(256, 2) void gemm_bt_kernel(
    const _Float16* __restrict__ A, const _Float16* __restrict__ Bt,
    const float* __restrict__ bias, void* __restrict__ Cout,
    int M, int N, int K)
{
    __shared__ __align__(16) char smem[32768];
    char* sA = smem;            // [128 rows][8 chunks16B] swizzled: chunk ^= row&7
    char* sB = smem + 16384;
    const int t = threadIdx.x, w = t >> 6, lane = t & 63;
    const int quad = lane >> 4, l15 = lane & 15;
    const int wr = w >> 1, wc = w & 1;
    const int n0 = blockIdx.x * 128, m0 = blockIdx.y * 128;

    const f32x4 vzero = {0.f, 0.f, 0.f, 0.f};
    f32x4 acc[4][4];
#pragma unroll
    for (int i = 0; i < 4; ++i)
#pragma unroll
        for (int j = 0; j < 4; ++j) acc[i][j] = vzero;

    const int kiters = K >> 6;
    for (int kk = 0; kk < kiters; ++kk) {
#pragma unroll
        for (int i = 0; i < 4; ++i) {
            int c = i * 256 + t;
            int row = c >> 3, kbs = c & 7, kact = kbs ^ (row & 7);
            gl_lds16(A + (size_t)(m0 + row) * K + kk * 64 + kact * 8,
                     sA + (i * 256 + w * 64) * 16);
        }
#pragma unroll
        for (int i = 0; i < 4; ++i) {
            int c = i * 256 + t;
            int row = c >> 3, kbs = c & 7, kact = kbs ^ (row & 7);
            gl_lds16(Bt + (size_t)(n0 + row) * K + kk * 64 + kact * 8,
                     sB + (i * 256 + w * 64) * 16);
        }
        __syncthreads();
#pragma unroll
        for (int ks = 0; ks < 2; ++ks) {
            half8 af[4], bf[4];
#pragma unroll
            for (int mt = 0; mt < 4; ++mt) {
                int row = wr * 64 + mt * 16 + l15;
                int kact = (ks * 4 + quad) ^ (l15 & 7);
                af[mt] = *(const half8*)(sA + row * 128 + kact * 16);
            }
#pragma unroll
            for (int nt = 0; nt < 4; ++nt) {
                int row = wc * 64 + nt * 16 + l15;
                int kact = (ks * 4 + quad) ^ (l15 & 7);
                bf[nt] = *(const half8*)(sB + row * 128 + kact * 16);
            }
#pragma unroll
            for (int mt = 0; mt < 4; ++mt)
#pragma unroll
                for (int nt = 0; nt < 4; ++nt)
                    acc[mt][nt] = __builtin_amdgcn_mfma_f32_16x16x32_f16(
                        af[mt], bf[nt], acc[mt][nt], 0, 0, 0);
        }
        __syncthreads();
    }

    // epilogue: C/D layout col=lane&15, row=quad*4+reg (m89-verified)
#pragma unroll
    for (int nt = 0; nt < 4; ++nt) {
        int col = n0 + wc * 64 + nt * 16 + l15;
        float bv = bias[col];
#pragma unroll
        for (int mt = 0; mt < 4; ++mt)
#pragma unroll
            for (int r = 0; r < 4; ++r) {
                int row = m0 + wr * 64 + mt * 16 + quad * 4 + r;
                float v = acc[mt][nt][r] + bv;
                if (BF16OUT) ((_Float16*)Cout)[(size_t)row * N + col] = (_Float16)v;
                else         ((float*)Cout)[(size_t)row * N + col] = v;
            }
    }
}

// ======================= flash attention (S^T orientation, 32 q/wave) =======================
// grid (32 bh, 16 qtiles heavy-first); block 256 = 4 waves; block covers 128 q,
// each wave 2 q-groups of 16. S^T = K·Q^T: C-layout of S^T IS the B-operand layout
// of mfma_16x16x16 -> P^T feeds PV via in-lane f32->f16 pack (no LDS round-trip).
// Shared kf/vf LDS reads feed 2 MFMAs each (2 q-groups) -> half the LDS/staging per FLOP.
__global__ __launch_bounds__(256, 3) void flash_kernel(
    const _Float16* __restrict__ qkv, const _Float16* __restrict__ vt,
    _Float16* __restrict__ attn)
{
    __shared__ __align__(16) char smem[34816];
    char* sK = smem;            // [64 kv][16 chunks16B] swizzled ^(row&15)
    char* sV = smem + 16384;    // [128 d][8 chunks16B]  swizzled ^(row&7)

    const int t = threadIdx.x, w = t >> 6, lane = t & 63;
    const int quad = lane >> 4, l15 = lane & 15;
    const int bh = blockIdx.x;
    const int qt = 15 - blockIdx.y;          // heavy tiles dispatched first
    const int b = bh >> 4, h = bh & 15;
    const int q0 = qt * 128;
    const int qw = q0 + w * 32;              // wave's q-column base (2 groups of 16)

    // Q fragments straight from global (once); B-operand layout == row-major reads
    half8 qf[2][4];
#pragma unroll
    for (int g = 0; g < 2; ++g)
#pragma unroll
        for (int ks = 0; ks < 4; ++ks) {
            const _Float16* p = qkv + (size_t)(b * Sc + qw + g * 16 + l15) * D3c +
                                h * 384 + ks * 32 + quad * 8;
            qf[g][ks] = *(const half8*)p;
        }

    const f32x4 vzero = {0.f, 0.f, 0.f, 0.f};
    f32x4 o[2][8];              // O^T[d = dt*16 + quad*4 + r][q-group g]
#pragma unroll
    for (int g = 0; g < 2; ++g)
#pragma unroll
        for (int dt = 0; dt < 8; ++dt) o[g][dt] = vzero;
    float m_st[2] = {-1e30f, -1e30f}, l_st[2] = {0.f, 0.f};

    const float kScale = 0.08838834764831845f * 1.4426950408889634f; // 1/sqrt(128)*log2(e)
    const int nkt = 2 * qt + 2;
    const int nkt_w = (qw + 95) >> 6;        // tiles this wave actually needs

    for (int kt = 0; kt < nkt; ++kt) {
        // ---- stage K tile [64 kv][128 d] ----
#pragma unroll
        for (int i = 0; i < 4; ++i) {
            int c = i * 256 + t;
            int row = c >> 4, kbs = c & 15, kact = kbs ^ (row & 15);
            gl_lds16(qkv + (size_t)(b * Sc + kt * 64 + row) * D3c + h * 384 + 128 + kact * 8,
                     sK + (i * 256 + w * 64) * 16);
        }
        // ---- stage Vt tile [128 d][64 kv] ----
#pragma unroll
        for (int i = 0; i < 4; ++i) {
            int c = i * 256 + t;
            int row = c >> 3, kbs = c & 7, kact = kbs ^ (row & 7);
            gl_lds16(vt + (size_t)(bh * HDc + row) * Sc + kt * 64 + kact * 8,
                     sV + (i * 256 + w * 64) * 16);
        }
        __syncthreads();

        if (kt < nkt_w) {
            // ---- S^T = K Q^T : per wave M=64 kv x N=16 q x2 groups, K=128 d ----
            f32x4 sf[2][4];
#pragma unroll
            for (int g = 0; g < 2; ++g)
#pragma unroll
                for (int kb = 0; kb < 4; ++kb) sf[g][kb] = vzero;
#pragma unroll
            for (int ks = 0; ks < 4; ++ks) {
#pragma unroll
                for (int kb = 0; kb < 4; ++kb) {
                    int row = kb * 16 + l15;
                    int slot = (ks * 4 + quad) ^ l15;
                    half8 kf = *(const half8*)(sK + row * 256 + slot * 16);
                    sf[0][kb] = __builtin_amdgcn_mfma_f32_16x16x32_f16(kf, qf[0][ks], sf[0][kb], 0, 0, 0);
                    sf[1][kb] = __builtin_amdgcn_mfma_f32_16x16x32_f16(kf, qf[1][ks], sf[1][kb], 0, 0, 0);
                }
            }

            // ---- online softmax per q-group; lane owns q = qw + g*16 + l15 ----
            half4 pb[2][4];
#pragma unroll
            for (int g = 0; g < 2; ++g) {
                const int qcol = qw + g * 16 + l15;
                const bool domask = (kt * 64 + 63 > qw + g * 16);
                float rm = -1e30f;
#pragma unroll
                for (int kb = 0; kb < 4; ++kb)
#pragma unroll
                    for (int r = 0; r < 4; ++r) {
                        float v = sf[g][kb][r] * kScale;
                        if (domask) {
                            int col = kt * 64 + kb * 16 + quad * 4 + r;
                            if (col > qcol) v = -1e30f;
                        }
                        sf[g][kb][r] = v;
                        rm = fmaxf(rm, v);
                    }
                rm = fmaxf(rm, __shfl_xor(rm, 16, 64));
                rm = fmaxf(rm, __shfl_xor(rm, 32, 64));
                float mn = fmaxf(m_st[g], rm);
                float alpha = __builtin_amdgcn_exp2f(m_st[g] - mn);
                m_st[g] = mn;

                float rs = 0.f;
#pragma unroll
                for (int kb = 0; kb < 4; ++kb)
#pragma unroll
                    for (int r = 0; r < 4; ++r) {
                        float p = __builtin_amdgcn_exp2f(sf[g][kb][r] - mn);
                        rs += p;
                        pb[g][kb][r] = (_Float16)p;
                    }
                rs += __shfl_xor(rs, 16, 64);
                rs += __shfl_xor(rs, 32, 64);
                l_st[g] = l_st[g] * alpha + rs;
#pragma unroll
                for (int dt = 0; dt < 8; ++dt)
#pragma unroll
                    for (int r = 0; r < 4; ++r) o[g][dt][r] *= alpha;
            }

            // ---- O^T += V^T P^T (mfma 16x16x16; vf shared across both q-groups) ----
#pragma unroll
            for (int kb = 0; kb < 4; ++kb) {
#pragma unroll
                for (int dt = 0; dt < 8; ++dt) {
                    int row = dt * 16 + l15;
                    int slot = (kb * 2 + (quad >> 1)) ^ (l15 & 7);
                    half4 vf = *(const half4*)(sV + row * 128 + slot * 16 + (quad & 1) * 8);
                    o[0][dt] = __builtin_amdgcn_mfma_f32_16x16x16f16(vf, pb[0][kb], o[0][dt], 0, 0, 0);
                    o[1][dt] = __builtin_amdgcn_mfma_f32_16x16x16f16(vf, pb[1][kb], o[1][dt], 0, 0, 0);
                }
            }
        }
        __syncthreads();   // LDS reads done before restaging
    }

    // ---- epilogue: O^T/l -> LDS transpose -> coalesced f16 store (128 q rows) ----
    char* sO = smem;      // [128 q][272B rows] (17x16B, conflict-shifted)
#pragma unroll
    for (int g = 0; g < 2; ++g) {
        float linv = 1.0f / l_st[g];
#pragma unroll
        for (int dt = 0; dt < 8; ++dt) {
            half4 hv;
#pragma unroll
            for (int r = 0; r < 4; ++r) hv[r] = (_Float16)(o[g][dt][r] * linv);
            *(half4*)(sO + (w * 32 + g * 16 + l15) * 272 + (dt * 16 + quad * 4) * 2) = hv;
        }
    }
    __syncthreads();
#pragma unroll
    for (int i = 0; i < 8; ++i) {
        int q = i * 16 + (t >> 4);
        int d = (t & 15) * 8;
        half8 hv = *(const half8*)(sO + q * 272 + d * 2);
        *(half8*)(attn + (size_t)(b * Sc + q0 + q) * Dc + h * HDc + d) = hv;
    }
}

// ======================= launch =======================
extern "C" void kernel_launch(void* const* d_in, const int* in_sizes, int n_in,
                              void* d_out, int out_size, void* d_ws, size_t ws_size,
                              hipStream_t stream)
{
    (void)in_sizes; (void)n_in; (void)out_size; (void)ws_size;
    const float* x    = (const float*)d_in[0];
    const float* Wqkv = (const float*)d_in[1];
    const float* bqkv = (const float*)d_in[2];
    const float* Wo   = (const float*)d_in[3];
    const float* bo   = (const float*)d_in[4];
    float* out = (float*)d_out;

    // workspace layout (f16 elems); attn aliases xb, vtg aliases wt1 (both dead by then)
    _Float16* xb  = (_Float16*)d_ws;                   // 4096*2048
    _Float16* wt1 = xb  + (size_t)Mc * Dc;             // 6144*2048 (Wqkv^T)
    _Float16* wt2 = wt1 + (size_t)D3c * Dc;            // 2048*2048 (Wo^T)
    _Float16* qkv = wt2 + (size_t)Dc * Dc;             // 4096*6144
    _Float16* vtg  = wt1;                              // 32*128*2048 (V^T), reuses wt1
    _Float16* attn = xb;                               // 4096*2048, reuses xb

    preproc_kernel<<<8192, 256, 0, stream>>>(x, Wqkv, Wo, xb, wt1, wt2);
    gemm_bt_kernel<1><<<dim3(D3c / 128, Mc / 128), 256, 0, stream>>>(
        xb, wt1, bqkv, qkv, Mc, D3c, Dc);
    transpose_v_kernel<<<dim3(Sc / 64, 2, Bc * Hc), 256, 0, stream>>>(
        (const uint16_t*)qkv, (uint16_t*)vtg);
    flash_kernel<<<dim3(Bc * Hc, 16), 256, 0, stream>>>(qkv, vtg, attn);
    gemm_bt_kernel<0><<<dim3(Dc / 128, Mc / 128), 256, 0, stream>>>(
        attn, wt2, bo, out, Mc, Dc, Dc);
}